// Round 8
// baseline (216.472 us; speedup 1.0000x reference)
//
#include <hip/hip_runtime.h>
#include <hip/hip_fp16.h>

#define N_NODES 100000
#define N_EDGES 1600000
#define K_DIM   128

#define CHUNK_LG 8
#define CHUNK    256                                     // nodes per bucket
#define NBKT     ((N_NODES + CHUNK - 1) / CHUNK)         // 391
#define CAP      4608                                    // mean 4092 + 8 sigma
#define EPB      1024                                    // edges per bucket-block
#define NBLK_A   ((N_EDGES + EPB - 1) / EPB)             // 1563
#define G1_BLOCKS ((N_NODES + 63) / 64)                  // 1563 gemm tiles

typedef _Float16 half8 __attribute__((ext_vector_type(8)));
typedef float    f32x4 __attribute__((ext_vector_type(4)));

// ============ fused: gemm1 (h1 = x@W1, f16 out)  ∥  edge bucketing ========
// even blocks: bucket chunk (bid>>1); odd blocks: GEMM tile (bid>>1).
// Interleave co-schedules the latency-bound bucket work with the
// stream/MFMA-bound GEMM across all CUs.
__global__ __launch_bounds__(256) void k_gemm1_bucket(
    const float* __restrict__ x, const float* __restrict__ W,
    _Float16* __restrict__ Hout,
    const int* __restrict__ row, const int* __restrict__ col,
    int* __restrict__ gcur, int* __restrict__ pairs)
{
    __shared__ __align__(16) char smem[128 * 136 * 2];   // 34816 B

    if (blockIdx.x & 1) {
        // ---------------- gemm path: NOUT=128, A fp32 ----------------
        constexpr int KD = K_DIM, NOUT = 128, NT = NOUT / 16;
        _Float16 (*Blds)[KD + 8] = reinterpret_cast<_Float16(*)[KD + 8]>(smem);

        for (int i = threadIdx.x * 4; i < KD * NOUT; i += 256 * 4) {
            int k = i / NOUT, n = i % NOUT;              // W row-major [KD][NOUT]
            float4 wv = *reinterpret_cast<const float4*>(W + i);
            Blds[n + 0][k] = (_Float16)wv.x;
            Blds[n + 1][k] = (_Float16)wv.y;
            Blds[n + 2][k] = (_Float16)wv.z;
            Blds[n + 3][k] = (_Float16)wv.w;
        }
        __syncthreads();

        const int tile = blockIdx.x >> 1;
        const int wave = threadIdx.x >> 6;
        const int lane = threadIdx.x & 63;
        const int r16  = lane & 15;
        const int kg   = lane >> 4;
        const int arow = tile * 64 + wave * 16 + r16;
        const bool rowok = arow < N_NODES;

        f32x4 acc[NT];
#pragma unroll
        for (int ct = 0; ct < NT; ++ct) acc[ct] = (f32x4){0.f, 0.f, 0.f, 0.f};

#pragma unroll
        for (int kc = 0; kc < KD / 32; ++kc) {
            const int k0 = kc * 32 + kg * 8;
            float4 xa = make_float4(0.f, 0.f, 0.f, 0.f), xb = xa;
            if (rowok) {
                const float4* ap = reinterpret_cast<const float4*>(
                    x + (size_t)arow * KD + k0);
                xa = ap[0]; xb = ap[1];
            }
            half8 a;
            a[0] = (_Float16)xa.x; a[1] = (_Float16)xa.y;
            a[2] = (_Float16)xa.z; a[3] = (_Float16)xa.w;
            a[4] = (_Float16)xb.x; a[5] = (_Float16)xb.y;
            a[6] = (_Float16)xb.z; a[7] = (_Float16)xb.w;
#pragma unroll
            for (int ct = 0; ct < NT; ++ct) {
                half8 b = *reinterpret_cast<const half8*>(&Blds[ct * 16 + r16][k0]);
                acc[ct] = __builtin_amdgcn_mfma_f32_16x16x32_f16(a, b, acc[ct], 0, 0, 0);
            }
        }

        const int orow0 = tile * 64 + wave * 16 + kg * 4;
#pragma unroll
        for (int r = 0; r < 4; ++r) {
            int orow = orow0 + r;
            if (orow < N_NODES) {
#pragma unroll
                for (int ct = 0; ct < NT; ++ct)
                    Hout[(size_t)orow * NOUT + ct * 16 + r16] = (_Float16)acc[ct][r];
            }
        }
    } else {
        // ---------------- bucket path: EPB=1024, 4 edges/thread ----------
        int* hist  = (int*)smem;           // [512]
        int* sbase = hist + 512;           // [512]
        int* lcur  = hist + 1024;          // [512]
        int t = threadIdx.x;
        for (int i = t; i < NBKT; i += 256) { hist[i] = 0; lcur[i] = 0; }
        __syncthreads();
        int base = (blockIdx.x >> 1) * EPB;
        int myb[4], myp[4];
#pragma unroll
        for (int j = 0; j < 4; ++j) {
            int i = base + t + j * 256;
            int b = -1, p = 0;
            if (i < N_EDGES) {
                int r = row[i], c = col[i];
                b = c >> CHUNK_LG;
                p = ((c & (CHUNK - 1)) << 17) | r;       // row < 2^17
                atomicAdd(&hist[b], 1);
            }
            myb[j] = b; myp[j] = p;
        }
        __syncthreads();
        for (int i = t; i < NBKT; i += 256) {
            int c = hist[i];
            sbase[i] = c ? atomicAdd(&gcur[i], c) : 0;
        }
        __syncthreads();
#pragma unroll
        for (int j = 0; j < 4; ++j) {
            int b = myb[j];
            if (b >= 0) {
                int pos = sbase[b] + atomicAdd(&lcur[b], 1);
                pairs[b * CAP + pos] = myp[j];
            }
        }
    }
}

// ============ Phase B: one block per bucket -> rowptr, dinv, srows ========
__global__ __launch_bounds__(256) void k_fillB(const int* __restrict__ gcur,
                                               const int* __restrict__ pairs,
                                               int* __restrict__ rowptr,
                                               float* __restrict__ dinv,
                                               int* __restrict__ srows) {
    __shared__ int red[256];
    __shared__ int psum[256];
    __shared__ int deg[CHUNK];
    __shared__ int curs[CHUNK];
    int b = blockIdx.x, t = threadIdx.x;

    // global base = sum gcur[0..b-1]
    int part = 0;
    for (int i = t; i < NBKT; i += 256)
        if (i < b) part += gcur[i];
    red[t] = part;
    __syncthreads();
    for (int off = 128; off; off >>= 1) {
        if (t < off) red[t] += red[t + off];
        __syncthreads();
    }
    int gb = red[0];
    int cnt = gcur[b];
    if (b == 0 && t == 0) rowptr[N_NODES] = N_EDGES;

    int nbase = b << CHUNK_LG;
    const int* mp = pairs + b * CAP;

    deg[t] = 0;
    __syncthreads();
    for (int i = t; i < cnt; i += 256) atomicAdd(&deg[mp[i] >> 17], 1);
    __syncthreads();

    int d = deg[t];
    psum[t] = d;
    __syncthreads();
    for (int off = 1; off < 256; off <<= 1) {
        int u = (t >= off) ? psum[t - off] : 0;
        __syncthreads();
        psum[t] += u;
        __syncthreads();
    }
    int o = gb + psum[t] - d;                 // exclusive
    curs[t] = o;
    int node = nbase + t;
    if (node < N_NODES) {
        rowptr[node] = o;
        dinv[node] = rsqrtf(1.f + (float)d);
    }
    __syncthreads();
    for (int i = t; i < cnt; i += 256) {
        int v = mp[i];
        int pos = atomicAdd(&curs[v >> 17], 1);
        srows[pos] = v & 0x1FFFF;
    }
}

// ============ layer-2 GEMM: h2 = relu(agg1+b1)@W2, f16 out ================
template<int NOUT>
__global__ __launch_bounds__(256) void k_gemm_mfma2(
    const _Float16* __restrict__ Ah, const float* __restrict__ W,
    const float* __restrict__ b_in, _Float16* __restrict__ Hout, int nrows)
{
    constexpr int KD = K_DIM;
    constexpr int NT = NOUT / 16;
    __shared__ _Float16 Blds[NOUT][KD + 8];

    for (int i = threadIdx.x * 4; i < KD * NOUT; i += 256 * 4) {
        int k = i / NOUT, n = i % NOUT;
        float4 wv = *reinterpret_cast<const float4*>(W + i);
        Blds[n + 0][k] = (_Float16)wv.x;
        Blds[n + 1][k] = (_Float16)wv.y;
        Blds[n + 2][k] = (_Float16)wv.z;
        Blds[n + 3][k] = (_Float16)wv.w;
    }
    __syncthreads();

    const int wave = threadIdx.x >> 6;
    const int lane = threadIdx.x & 63;
    const int r16  = lane & 15;
    const int kg   = lane >> 4;
    const int arow = blockIdx.x * 64 + wave * 16 + r16;
    const bool rowok = arow < nrows;

    f32x4 acc[NT];
#pragma unroll
    for (int ct = 0; ct < NT; ++ct) acc[ct] = (f32x4){0.f, 0.f, 0.f, 0.f};

#pragma unroll
    for (int kc = 0; kc < KD / 32; ++kc) {
        const int k0 = kc * 32 + kg * 8;
        uint4 raw = make_uint4(0, 0, 0, 0);
        if (rowok)
            raw = *reinterpret_cast<const uint4*>(Ah + (size_t)arow * KD + k0);
        union { uint4 u; _Float16 h[8]; } U; U.u = raw;
        float4 bA = *reinterpret_cast<const float4*>(b_in + k0);
        float4 bB = *reinterpret_cast<const float4*>(b_in + k0 + 4);
        half8 a;
        a[0] = (_Float16)fmaxf((float)U.h[0] + bA.x, 0.f);
        a[1] = (_Float16)fmaxf((float)U.h[1] + bA.y, 0.f);
        a[2] = (_Float16)fmaxf((float)U.h[2] + bA.z, 0.f);
        a[3] = (_Float16)fmaxf((float)U.h[3] + bA.w, 0.f);
        a[4] = (_Float16)fmaxf((float)U.h[4] + bB.x, 0.f);
        a[5] = (_Float16)fmaxf((float)U.h[5] + bB.y, 0.f);
        a[6] = (_Float16)fmaxf((float)U.h[6] + bB.z, 0.f);
        a[7] = (_Float16)fmaxf((float)U.h[7] + bB.w, 0.f);
#pragma unroll
        for (int ct = 0; ct < NT; ++ct) {
            half8 b = *reinterpret_cast<const half8*>(&Blds[ct * 16 + r16][k0]);
            acc[ct] = __builtin_amdgcn_mfma_f32_16x16x32_f16(a, b, acc[ct], 0, 0, 0);
        }
    }

    const int orow0 = blockIdx.x * 64 + wave * 16 + kg * 4;
#pragma unroll
    for (int r = 0; r < 4; ++r) {
        int orow = orow0 + r;
        if (orow < nrows) {
#pragma unroll
            for (int ct = 0; ct < NT; ++ct)
                Hout[(size_t)orow * NOUT + ct * 16 + r16] = (_Float16)acc[ct][r];
        }
    }
}

// ---------------- gather (f16 source): one wave per destination ----------
__device__ __forceinline__ void fma8(uint4 v, float wgt, float (&acc)[8]) {
    union { uint4 u; _Float16 h[8]; } U;
    U.u = v;
#pragma unroll
    for (int j = 0; j < 8; ++j)
        acc[j] = fmaf((float)U.h[j], wgt, acc[j]);
}

// OUT[i] = sum_e H[row_e]*dinv_r*dinv_i + H[i]*dinv_i^2 (+bias)
// GR edges per step, 2-deep software pipeline (no redundant tail loads
// except in the final partial chunk).
template<int F, bool OUT_HALF>
__global__ __launch_bounds__(256) void k_gather_h(
    const int* __restrict__ rowptr, const int* __restrict__ srows,
    const float* __restrict__ dinv, const _Float16* __restrict__ H,
    const float* __restrict__ bias, void* __restrict__ OUT, int n)
{
    constexpr int LPR = F / 8;     // lanes per row (16 or 8), 8 f16 per lane
    constexpr int GR  = 64 / LPR;  // rows covered per wave-load (4 or 8)
    int w = blockIdx.x * 4 + (threadIdx.x >> 6);
    if (w >= n) return;
    int lane = threadIdx.x & 63;
    int g = lane / LPR;
    int c = lane % LPR;            // uint4 slot within row
    float di = dinv[w];
    int s = rowptr[w], e = rowptr[w + 1];
    const uint4* Hp = reinterpret_cast<const uint4*>(H);

    float acc[8];
#pragma unroll
    for (int j = 0; j < 8; ++j) acc[j] = 0.f;
    uint4 hv = Hp[(size_t)w * LPR + c];                 // self row
    fma8(hv, (g == 0) ? di * di : 0.f, acc);

    if (s < e) {
        int k0 = s + g;
        int kc = min(k0, e - 1);
        int r  = srows[kc];
        float wcur = (k0 < e) ? dinv[r] * di : 0.f;
        uint4 hcur = Hp[(size_t)r * LPR + c];
        for (int k = s + GR; k < e; k += GR) {
            int k1  = k + g;
            int kc1 = min(k1, e - 1);
            int r1  = srows[kc1];
            float wnxt = (k1 < e) ? dinv[r1] * di : 0.f;
            uint4 hnxt = Hp[(size_t)r1 * LPR + c];
            fma8(hcur, wcur, acc);
            wcur = wnxt; hcur = hnxt;
        }
        fma8(hcur, wcur, acc);
    }

#pragma unroll
    for (int m = 32; m >= LPR; m >>= 1) {               // combine row groups
#pragma unroll
        for (int j = 0; j < 8; ++j)
            acc[j] += __shfl_xor(acc[j], m, 64);
    }

    if (g == 0) {
        if constexpr (OUT_HALF) {
            union { uint4 u; __half2 h[4]; } P;
#pragma unroll
            for (int j = 0; j < 4; ++j)
                P.h[j] = __floats2half2_rn(acc[2 * j], acc[2 * j + 1]);
            reinterpret_cast<uint4*>(OUT)[(size_t)w * LPR + c] = P.u;
        } else {
            const float4* bp = reinterpret_cast<const float4*>(bias + c * 8);
            float4 b0 = bp[0], b1 = bp[1];
            float4 o0 = make_float4(acc[0] + b0.x, acc[1] + b0.y,
                                    acc[2] + b0.z, acc[3] + b0.w);
            float4 o1 = make_float4(acc[4] + b1.x, acc[5] + b1.y,
                                    acc[6] + b1.z, acc[7] + b1.w);
            float* op = (float*)OUT + (size_t)w * F + c * 8;
            *reinterpret_cast<float4*>(op)     = o0;
            *reinterpret_cast<float4*>(op + 4) = o1;
        }
    }
}

// ---------------- launch ----------------

extern "C" void kernel_launch(void* const* d_in, const int* in_sizes, int n_in,
                              void* d_out, int out_size, void* d_ws, size_t ws_size,
                              hipStream_t stream) {
    const float* x  = (const float*)d_in[0];
    const int*   ei = (const int*)  d_in[1];
    const float* W1 = (const float*)d_in[2];
    const float* b1 = (const float*)d_in[3];
    const float* W2 = (const float*)d_in[4];
    const float* b2 = (const float*)d_in[5];
    float* out = (float*)d_out;

    const int* row = ei;             // sources
    const int* col = ei + N_EDGES;   // targets

    // workspace layout
    char* ws = (char*)d_ws;
    int*   gcur   = (int*)ws;                                      // NBKT
    int*   rowptr = gcur + 512;                                    // N+1
    float* dinv   = (float*)(rowptr + ((N_NODES + 256) & ~255));   // N
    int*   srows  = (int*)(dinv + ((N_NODES + 255) & ~255));       // E
    _Float16* bufH   = (_Float16*)(srows + ((N_EDGES + 255) & ~255)); // N*128 f16
    _Float16* bufAgg = bufH + (size_t)N_NODES * 128;               // N*128 f16
    int*   pairs  = (int*)bufAgg;    // NBKT*CAP ints (7.2MB), dead before gather1

    // 1) zero bucket cursors; fused gemm1 ∥ edge bucketing (interleaved)
    hipMemsetAsync(gcur, 0, NBKT * sizeof(int), stream);
    k_gemm1_bucket<<<G1_BLOCKS + NBLK_A, 256, 0, stream>>>(
        x, W1, bufH, row, col, gcur, pairs);

    // 2) CSR finalize: rowptr, dinv, srows
    k_fillB<<<NBKT, 256, 0, stream>>>(gcur, pairs, rowptr, dinv, srows);

    // 3) agg1 = gather(h1), f16 out
    k_gather_h<128, true><<<(N_NODES + 3) / 4, 256, 0, stream>>>(
        rowptr, srows, dinv, bufH, nullptr, bufAgg, N_NODES);

    // 4) h2 = relu(agg1+b1)@W2 (f16 out)
    k_gemm_mfma2<64><<<(N_NODES + 63) / 64, 256, 0, stream>>>(
        bufAgg, W2, b1, bufH, N_NODES);

    // 5) out = gather(h2) + b2 (fp32 out)
    k_gather_h<64, false><<<(N_NODES + 3) / 4, 256, 0, stream>>>(
        rowptr, srows, dinv, bufH, b2, out, N_NODES);
}

// Round 9
// 204.937 us; speedup vs baseline: 1.0563x; 1.0563x over previous
//
#include <hip/hip_runtime.h>
#include <hip/hip_fp16.h>

#define N_NODES 100000
#define N_EDGES 1600000
#define K_DIM   128

#define CHUNK_LG 8
#define CHUNK    256                                     // nodes per bucket
#define NBKT     ((N_NODES + CHUNK - 1) / CHUNK)         // 391
#define CAP      4608                                    // mean 4092 + 8 sigma
#define EPB      4096                                    // edges per bucket-block
#define NBLK_A   ((N_EDGES + EPB - 1) / EPB)             // 391
#define G1_BLOCKS ((N_NODES + 63) / 64)                  // 1563 gemm tiles
#define NBLK_TOT (G1_BLOCKS + NBLK_A)                    // 1954

typedef _Float16 half8 __attribute__((ext_vector_type(8)));
typedef float    f32x4 __attribute__((ext_vector_type(4)));

// ============ fused: gemm1 (h1 = x@W1, f16 out)  ∥  edge bucketing ========
// bid%5==0 -> bucket block (391 of them, EPB=4096); else GEMM tile.
// 1:4 interleave co-schedules latency-bound bucketing with the MFMA GEMM
// without multiplying per-block bucket overhead (R8 lesson).
__global__ __launch_bounds__(256) void k_gemm1_bucket(
    const float* __restrict__ x, const float* __restrict__ W,
    _Float16* __restrict__ Hout,
    const int* __restrict__ row, const int* __restrict__ col,
    int* __restrict__ gcur, int* __restrict__ pairs)
{
    __shared__ __align__(16) char smem[128 * 136 * 2];   // 34816 B

    if (blockIdx.x % 5 != 0) {
        // ---------------- gemm path: NOUT=128, A fp32 ----------------
        constexpr int KD = K_DIM, NOUT = 128, NT = NOUT / 16;
        _Float16 (*Blds)[KD + 8] = reinterpret_cast<_Float16(*)[KD + 8]>(smem);

        for (int i = threadIdx.x * 4; i < KD * NOUT; i += 256 * 4) {
            int k = i / NOUT, n = i % NOUT;              // W row-major [KD][NOUT]
            float4 wv = *reinterpret_cast<const float4*>(W + i);
            Blds[n + 0][k] = (_Float16)wv.x;
            Blds[n + 1][k] = (_Float16)wv.y;
            Blds[n + 2][k] = (_Float16)wv.z;
            Blds[n + 3][k] = (_Float16)wv.w;
        }
        __syncthreads();

        const int tile = blockIdx.x - blockIdx.x / 5 - 1;
        const int wave = threadIdx.x >> 6;
        const int lane = threadIdx.x & 63;
        const int r16  = lane & 15;
        const int kg   = lane >> 4;
        const int arow = tile * 64 + wave * 16 + r16;
        const bool rowok = arow < N_NODES;

        f32x4 acc[NT];
#pragma unroll
        for (int ct = 0; ct < NT; ++ct) acc[ct] = (f32x4){0.f, 0.f, 0.f, 0.f};

#pragma unroll
        for (int kc = 0; kc < KD / 32; ++kc) {
            const int k0 = kc * 32 + kg * 8;
            float4 xa = make_float4(0.f, 0.f, 0.f, 0.f), xb = xa;
            if (rowok) {
                const float4* ap = reinterpret_cast<const float4*>(
                    x + (size_t)arow * KD + k0);
                xa = ap[0]; xb = ap[1];
            }
            half8 a;
            a[0] = (_Float16)xa.x; a[1] = (_Float16)xa.y;
            a[2] = (_Float16)xa.z; a[3] = (_Float16)xa.w;
            a[4] = (_Float16)xb.x; a[5] = (_Float16)xb.y;
            a[6] = (_Float16)xb.z; a[7] = (_Float16)xb.w;
#pragma unroll
            for (int ct = 0; ct < NT; ++ct) {
                half8 b = *reinterpret_cast<const half8*>(&Blds[ct * 16 + r16][k0]);
                acc[ct] = __builtin_amdgcn_mfma_f32_16x16x32_f16(a, b, acc[ct], 0, 0, 0);
            }
        }

        const int orow0 = tile * 64 + wave * 16 + kg * 4;
#pragma unroll
        for (int r = 0; r < 4; ++r) {
            int orow = orow0 + r;
            if (orow < N_NODES) {
#pragma unroll
                for (int ct = 0; ct < NT; ++ct)
                    Hout[(size_t)orow * NOUT + ct * 16 + r16] = (_Float16)acc[ct][r];
            }
        }
    } else {
        // ---------------- bucket path: EPB=4096, 16 edges/thread ---------
        int* hist  = (int*)smem;           // [512]
        int* sbase = hist + 512;           // [512]
        int* lcur  = hist + 1024;          // [512]
        int t = threadIdx.x;
        for (int i = t; i < NBKT; i += 256) { hist[i] = 0; lcur[i] = 0; }
        __syncthreads();
        int base = (blockIdx.x / 5) * EPB;
        int myb[16], myp[16];
#pragma unroll
        for (int j = 0; j < 16; ++j) {
            int i = base + t + j * 256;
            int b = -1, p = 0;
            if (i < N_EDGES) {
                int r = row[i], c = col[i];
                b = c >> CHUNK_LG;
                p = ((c & (CHUNK - 1)) << 17) | r;       // row < 2^17
                atomicAdd(&hist[b], 1);
            }
            myb[j] = b; myp[j] = p;
        }
        __syncthreads();
        for (int i = t; i < NBKT; i += 256) {
            int c = hist[i];
            sbase[i] = c ? atomicAdd(&gcur[i], c) : 0;
        }
        __syncthreads();
#pragma unroll
        for (int j = 0; j < 16; ++j) {
            int b = myb[j];
            if (b >= 0) {
                int pos = sbase[b] + atomicAdd(&lcur[b], 1);
                pairs[b * CAP + pos] = myp[j];
            }
        }
    }
}

// ============ Phase B: one block per bucket -> rowptr, dinv, srows ========
// pairs staged through LDS: one global read, hist + fill from LDS.
__global__ __launch_bounds__(256) void k_fillB(const int* __restrict__ gcur,
                                               const int* __restrict__ pairs,
                                               int* __restrict__ rowptr,
                                               float* __restrict__ dinv,
                                               int* __restrict__ srows) {
    __shared__ int mpl[CAP];
    __shared__ int red[256];
    __shared__ int psum[256];
    __shared__ int deg[CHUNK];
    __shared__ int curs[CHUNK];
    int b = blockIdx.x, t = threadIdx.x;

    // global base = sum gcur[0..b-1]
    int part = 0;
    for (int i = t; i < NBKT; i += 256)
        if (i < b) part += gcur[i];
    red[t] = part;
    deg[t] = 0;
    __syncthreads();
    for (int off = 128; off; off >>= 1) {
        if (t < off) red[t] += red[t + off];
        __syncthreads();
    }
    int gb = red[0];
    int cnt = gcur[b];
    if (b == 0 && t == 0) rowptr[N_NODES] = N_EDGES;

    int nbase = b << CHUNK_LG;
    const int* mp = pairs + b * CAP;

    // stage + histogram in one pass
    for (int i = t; i < cnt; i += 256) {
        int v = mp[i];
        mpl[i] = v;
        atomicAdd(&deg[v >> 17], 1);
    }
    __syncthreads();

    int d = deg[t];
    psum[t] = d;
    __syncthreads();
    for (int off = 1; off < 256; off <<= 1) {
        int u = (t >= off) ? psum[t - off] : 0;
        __syncthreads();
        psum[t] += u;
        __syncthreads();
    }
    int o = gb + psum[t] - d;                 // exclusive
    curs[t] = o;
    int node = nbase + t;
    if (node < N_NODES) {
        rowptr[node] = o;
        dinv[node] = rsqrtf(1.f + (float)d);
    }
    __syncthreads();
    for (int i = t; i < cnt; i += 256) {
        int v = mpl[i];
        int pos = atomicAdd(&curs[v >> 17], 1);
        srows[pos] = v & 0x1FFFF;
    }
}

// ---------------- f16 fma helper ----------------
__device__ __forceinline__ void fma8(uint4 v, float wgt, float (&acc)[8]) {
    union { uint4 u; _Float16 h[8]; } U;
    U.u = v;
#pragma unroll
    for (int j = 0; j < 8; ++j)
        acc[j] = fmaf((float)U.h[j], wgt, acc[j]);
}

// ============ fused gather1 + gemm2 ========================================
// Block = 32 destination nodes, 512 threads (8 waves).
// Phase 1: stage W2 -> LDS (f16, padded).  Phase 2: each wave gathers 4
// nodes (agg = S·h1 row) into LDS aggT (f16).  Phase 3 (after one sync):
// each wave computes one 16x16 tile of h2 = relu(aggT+b1) @ W2.
#define GG_NODES 32
__global__ __launch_bounds__(512, 6) void k_gather_gemm2(
    const int* __restrict__ rowptr, const int* __restrict__ srows,
    const float* __restrict__ dinv, const _Float16* __restrict__ H,
    const float* __restrict__ W2, const float* __restrict__ b1,
    _Float16* __restrict__ H2, int n)
{
    __shared__ _Float16 Wlds[64][K_DIM + 8];        // [n][k], 17408 B
    __shared__ _Float16 aggT[GG_NODES][K_DIM + 8];  //  8704 B

    // stage W2 (f32 row-major [128][64]) -> Wlds[n][k]
    for (int i = threadIdx.x * 4; i < K_DIM * 64; i += 512 * 4) {
        int k = i >> 6, nn = i & 63;
        float4 wv = *reinterpret_cast<const float4*>(W2 + i);
        Wlds[nn + 0][k] = (_Float16)wv.x;
        Wlds[nn + 1][k] = (_Float16)wv.y;
        Wlds[nn + 2][k] = (_Float16)wv.z;
        Wlds[nn + 3][k] = (_Float16)wv.w;
    }

    const int wid  = threadIdx.x >> 6;    // 0..7
    const int lane = threadIdx.x & 63;
    const int g = lane >> 4;              // 0..3 (4 rows per wave-load)
    const int c = lane & 15;              // uint4 slot within 128-f16 row
    const uint4* Hp = reinterpret_cast<const uint4*>(H);

    // ---- gather phase: wave wid handles nodes local = wid*4 + rr ----
    for (int rr = 0; rr < 4; ++rr) {
        int local = wid * 4 + rr;
        int w = blockIdx.x * GG_NODES + local;
        float acc[8];
#pragma unroll
        for (int j = 0; j < 8; ++j) acc[j] = 0.f;
        if (w < n) {
            float di = dinv[w];
            int s = rowptr[w], e = rowptr[w + 1];
            uint4 hv = Hp[(size_t)w * 16 + c];               // self row
            fma8(hv, (g == 0) ? di * di : 0.f, acc);
            if (s < e) {
                int k0 = s + g;
                int kc = min(k0, e - 1);
                int r  = srows[kc];
                float wcur = (k0 < e) ? dinv[r] * di : 0.f;
                uint4 hcur = Hp[(size_t)r * 16 + c];
                for (int k = s + 4; k < e; k += 4) {
                    int k1  = k + g;
                    int kc1 = min(k1, e - 1);
                    int r1  = srows[kc1];
                    float wnxt = (k1 < e) ? dinv[r1] * di : 0.f;
                    uint4 hnxt = Hp[(size_t)r1 * 16 + c];
                    fma8(hcur, wcur, acc);
                    wcur = wnxt; hcur = hnxt;
                }
                fma8(hcur, wcur, acc);
            }
        }
#pragma unroll
        for (int m = 32; m >= 16; m >>= 1) {
#pragma unroll
            for (int j = 0; j < 8; ++j)
                acc[j] += __shfl_xor(acc[j], m, 64);
        }
        if (g == 0) {
            union { uint4 u; __half2 h[4]; } P;
#pragma unroll
            for (int j = 0; j < 4; ++j)
                P.h[j] = __floats2half2_rn(acc[2 * j], acc[2 * j + 1]);
            *reinterpret_cast<uint4*>(&aggT[local][c * 8]) = P.u;
        }
    }
    __syncthreads();

    // ---- gemm phase: wave wid -> rows (wid&1)*16, cols (wid>>1)*16 ----
    const int r16 = lane & 15;
    const int kg  = lane >> 4;
    const int rtile = (wid & 1) * 16;
    const int ctile = (wid >> 1) * 16;
    f32x4 acc2 = (f32x4){0.f, 0.f, 0.f, 0.f};
#pragma unroll
    for (int kc = 0; kc < K_DIM / 32; ++kc) {
        const int k0 = kc * 32 + kg * 8;
        half8 raw = *reinterpret_cast<const half8*>(&aggT[rtile + r16][k0]);
        float4 bA = *reinterpret_cast<const float4*>(b1 + k0);
        float4 bB = *reinterpret_cast<const float4*>(b1 + k0 + 4);
        half8 a;
        a[0] = (_Float16)fmaxf((float)raw[0] + bA.x, 0.f);
        a[1] = (_Float16)fmaxf((float)raw[1] + bA.y, 0.f);
        a[2] = (_Float16)fmaxf((float)raw[2] + bA.z, 0.f);
        a[3] = (_Float16)fmaxf((float)raw[3] + bA.w, 0.f);
        a[4] = (_Float16)fmaxf((float)raw[4] + bB.x, 0.f);
        a[5] = (_Float16)fmaxf((float)raw[5] + bB.y, 0.f);
        a[6] = (_Float16)fmaxf((float)raw[6] + bB.z, 0.f);
        a[7] = (_Float16)fmaxf((float)raw[7] + bB.w, 0.f);
        half8 b = *reinterpret_cast<const half8*>(&Wlds[ctile + r16][k0]);
        acc2 = __builtin_amdgcn_mfma_f32_16x16x32_f16(a, b, acc2, 0, 0, 0);
    }
    const int colg = ctile + r16;
    const int row0 = blockIdx.x * GG_NODES + rtile + kg * 4;
#pragma unroll
    for (int r = 0; r < 4; ++r) {
        int orow = row0 + r;
        if (orow < n)
            H2[(size_t)orow * 64 + colg] = (_Float16)acc2[r];
    }
}

// ---------------- gather2 (F=64, fp32 out + bias): one wave per node -----
template<int F, bool OUT_HALF>
__global__ __launch_bounds__(256) void k_gather_h(
    const int* __restrict__ rowptr, const int* __restrict__ srows,
    const float* __restrict__ dinv, const _Float16* __restrict__ H,
    const float* __restrict__ bias, void* __restrict__ OUT, int n)
{
    constexpr int LPR = F / 8;     // lanes per row (8 for F=64)
    constexpr int GR  = 64 / LPR;  // rows covered per wave-load (8)
    int w = blockIdx.x * 4 + (threadIdx.x >> 6);
    if (w >= n) return;
    int lane = threadIdx.x & 63;
    int g = lane / LPR;
    int c = lane % LPR;            // uint4 slot within row
    float di = dinv[w];
    int s = rowptr[w], e = rowptr[w + 1];
    const uint4* Hp = reinterpret_cast<const uint4*>(H);

    float acc[8];
#pragma unroll
    for (int j = 0; j < 8; ++j) acc[j] = 0.f;
    uint4 hv = Hp[(size_t)w * LPR + c];                 // self row
    fma8(hv, (g == 0) ? di * di : 0.f, acc);

    if (s < e) {
        int k0 = s + g;
        int kc = min(k0, e - 1);
        int r  = srows[kc];
        float wcur = (k0 < e) ? dinv[r] * di : 0.f;
        uint4 hcur = Hp[(size_t)r * LPR + c];
        for (int k = s + GR; k < e; k += GR) {
            int k1  = k + g;
            int kc1 = min(k1, e - 1);
            int r1  = srows[kc1];
            float wnxt = (k1 < e) ? dinv[r1] * di : 0.f;
            uint4 hnxt = Hp[(size_t)r1 * LPR + c];
            fma8(hcur, wcur, acc);
            wcur = wnxt; hcur = hnxt;
        }
        fma8(hcur, wcur, acc);
    }

#pragma unroll
    for (int m = 32; m >= LPR; m >>= 1) {
#pragma unroll
        for (int j = 0; j < 8; ++j)
            acc[j] += __shfl_xor(acc[j], m, 64);
    }

    if (g == 0) {
        if constexpr (OUT_HALF) {
            union { uint4 u; __half2 h[4]; } P;
#pragma unroll
            for (int j = 0; j < 4; ++j)
                P.h[j] = __floats2half2_rn(acc[2 * j], acc[2 * j + 1]);
            reinterpret_cast<uint4*>(OUT)[(size_t)w * LPR + c] = P.u;
        } else {
            const float4* bp = reinterpret_cast<const float4*>(bias + c * 8);
            float4 b0 = bp[0], b1v = bp[1];
            float4 o0 = make_float4(acc[0] + b0.x, acc[1] + b0.y,
                                    acc[2] + b0.z, acc[3] + b0.w);
            float4 o1 = make_float4(acc[4] + b1v.x, acc[5] + b1v.y,
                                    acc[6] + b1v.z, acc[7] + b1v.w);
            float* op = (float*)OUT + (size_t)w * F + c * 8;
            *reinterpret_cast<float4*>(op)     = o0;
            *reinterpret_cast<float4*>(op + 4) = o1;
        }
    }
}

// ---------------- launch ----------------

extern "C" void kernel_launch(void* const* d_in, const int* in_sizes, int n_in,
                              void* d_out, int out_size, void* d_ws, size_t ws_size,
                              hipStream_t stream) {
    const float* x  = (const float*)d_in[0];
    const int*   ei = (const int*)  d_in[1];
    const float* W1 = (const float*)d_in[2];
    const float* b1 = (const float*)d_in[3];
    const float* W2 = (const float*)d_in[4];
    const float* b2 = (const float*)d_in[5];
    float* out = (float*)d_out;

    const int* row = ei;             // sources
    const int* col = ei + N_EDGES;   // targets

    // workspace layout
    char* ws = (char*)d_ws;
    int*   gcur   = (int*)ws;                                      // NBKT
    int*   rowptr = gcur + 512;                                    // N+1
    float* dinv   = (float*)(rowptr + ((N_NODES + 256) & ~255));   // N
    int*   srows  = (int*)(dinv + ((N_NODES + 255) & ~255));       // E
    _Float16* bufH  = (_Float16*)(srows + ((N_EDGES + 255) & ~255)); // N*128 f16 (h1)
    _Float16* bufH2 = bufH + (size_t)N_NODES * 128;                // N*64 f16 (h2)
    int*   pairs  = (int*)(bufH2 + (size_t)N_NODES * 64);          // NBKT*CAP ints

    // 1) zero bucket cursors; fused gemm1 ∥ edge bucketing (1:4 interleave)
    hipMemsetAsync(gcur, 0, NBKT * sizeof(int), stream);
    k_gemm1_bucket<<<NBLK_TOT, 256, 0, stream>>>(
        x, W1, bufH, row, col, gcur, pairs);

    // 2) CSR finalize: rowptr, dinv, srows
    k_fillB<<<NBKT, 256, 0, stream>>>(gcur, pairs, rowptr, dinv, srows);

    // 3+4) agg1 = gather(h1) -> LDS; h2 = relu(agg1+b1)@W2 (f16 out)
    k_gather_gemm2<<<(N_NODES + GG_NODES - 1) / GG_NODES, 512, 0, stream>>>(
        rowptr, srows, dinv, bufH, W2, b1, bufH2, N_NODES);

    // 5) out = gather(h2) + b2 (fp32 out)
    k_gather_h<64, false><<<(N_NODES + 3) / 4, 256, 0, stream>>>(
        rowptr, srows, dinv, bufH2, b2, out, N_NODES);
}

// Round 10
// 191.802 us; speedup vs baseline: 1.1286x; 1.0685x over previous
//
#include <hip/hip_runtime.h>
#include <hip/hip_fp16.h>

#define N_NODES 100000
#define N_EDGES 1600000
#define K_DIM   128

#define CHUNK_LG 8
#define CHUNK    256                                     // nodes per bucket
#define NBKT     ((N_NODES + CHUNK - 1) / CHUNK)         // 391
#define CAP      4608                                    // mean 4092 + 8 sigma
#define EPB      4096                                    // edges per bucket-block
#define NBLK_A   ((N_EDGES + EPB - 1) / EPB)             // 391
#define G1_BLOCKS ((N_NODES + 63) / 64)                  // 1563 gemm tiles
#define NBLK_TOT (G1_BLOCKS + NBLK_A)                    // 1954

typedef _Float16 half8 __attribute__((ext_vector_type(8)));
typedef float    f32x4 __attribute__((ext_vector_type(4)));

// ============ one-shot: W1,W2 -> f16 transposed Wt[n][k] ==================
// Wt1: [128][128], Wt2: [64][128]. Strided scalar reads (tiny, L2-hot),
// coalesced half8 writes. Lets every GEMM block stage LDS conflict-free.
__global__ __launch_bounds__(256) void k_prepW(const float* __restrict__ W1,
                                               const float* __restrict__ W2,
                                               _Float16* __restrict__ Wt1,
                                               _Float16* __restrict__ Wt2) {
    int c = blockIdx.x * 256 + threadIdx.x;   // 3072 chunks of 8
    const float* W; _Float16* Wt; int nout;
    if (c < 2048) { W = W1; Wt = Wt1; nout = 128; }
    else          { W = W2; Wt = Wt2; nout = 64; c -= 2048; }
    int n  = c >> 4;
    int k0 = (c & 15) * 8;
    half8 v;
#pragma unroll
    for (int j = 0; j < 8; ++j)
        v[j] = (_Float16)W[(size_t)(k0 + j) * nout + n];
    *reinterpret_cast<half8*>(Wt + (size_t)n * K_DIM + k0) = v;
}

// ============ fused: gemm1 (h1 = x@W1, f16 out)  ∥  edge bucketing ========
// bid%5==0 -> bucket block (391, EPB=4096); else GEMM tile (1563).
__global__ __launch_bounds__(256) void k_gemm1_bucket(
    const float* __restrict__ x, const _Float16* __restrict__ Wt,
    _Float16* __restrict__ Hout,
    const int* __restrict__ row, const int* __restrict__ col,
    int* __restrict__ gcur, int* __restrict__ pairs)
{
    __shared__ __align__(16) char smem[128 * 136 * 2];   // 34816 B

    if (blockIdx.x % 5 != 0) {
        // ---------------- gemm path: NOUT=128, A fp32 ----------------
        constexpr int KD = K_DIM, NOUT = 128, NT = NOUT / 16;
        _Float16 (*Blds)[KD + 8] = reinterpret_cast<_Float16(*)[KD + 8]>(smem);

        // stage Wt (f16 [n][k] packed) -> Blds[n][k] (+8 pad); 2-way max
        for (int i = threadIdx.x; i < NOUT * (KD / 8); i += 256) {
            int n = i >> 4, k0 = (i & 15) * 8;
            *reinterpret_cast<half8*>(&Blds[n][k0]) =
                *reinterpret_cast<const half8*>(Wt + (size_t)n * KD + k0);
        }
        __syncthreads();

        const int tile = blockIdx.x - blockIdx.x / 5 - 1;
        const int wave = threadIdx.x >> 6;
        const int lane = threadIdx.x & 63;
        const int r16  = lane & 15;
        const int kg   = lane >> 4;
        const int arow = tile * 64 + wave * 16 + r16;
        const bool rowok = arow < N_NODES;

        f32x4 acc[NT];
#pragma unroll
        for (int ct = 0; ct < NT; ++ct) acc[ct] = (f32x4){0.f, 0.f, 0.f, 0.f};

#pragma unroll
        for (int kc = 0; kc < KD / 32; ++kc) {
            const int k0 = kc * 32 + kg * 8;
            float4 xa = make_float4(0.f, 0.f, 0.f, 0.f), xb = xa;
            if (rowok) {
                const float4* ap = reinterpret_cast<const float4*>(
                    x + (size_t)arow * KD + k0);
                xa = ap[0]; xb = ap[1];
            }
            half8 a;
            a[0] = (_Float16)xa.x; a[1] = (_Float16)xa.y;
            a[2] = (_Float16)xa.z; a[3] = (_Float16)xa.w;
            a[4] = (_Float16)xb.x; a[5] = (_Float16)xb.y;
            a[6] = (_Float16)xb.z; a[7] = (_Float16)xb.w;
#pragma unroll
            for (int ct = 0; ct < NT; ++ct) {
                half8 b = *reinterpret_cast<const half8*>(&Blds[ct * 16 + r16][k0]);
                acc[ct] = __builtin_amdgcn_mfma_f32_16x16x32_f16(a, b, acc[ct], 0, 0, 0);
            }
        }

        const int orow0 = tile * 64 + wave * 16 + kg * 4;
#pragma unroll
        for (int r = 0; r < 4; ++r) {
            int orow = orow0 + r;
            if (orow < N_NODES) {
#pragma unroll
                for (int ct = 0; ct < NT; ++ct)
                    Hout[(size_t)orow * NOUT + ct * 16 + r16] = (_Float16)acc[ct][r];
            }
        }
    } else {
        // ---------------- bucket path: EPB=4096, 16 edges/thread ---------
        int* hist  = (int*)smem;           // [512]
        int* sbase = hist + 512;           // [512]
        int* lcur  = hist + 1024;          // [512]
        int t = threadIdx.x;
        for (int i = t; i < NBKT; i += 256) { hist[i] = 0; lcur[i] = 0; }
        __syncthreads();
        int base = (blockIdx.x / 5) * EPB;
        int myb[16], myp[16];
#pragma unroll
        for (int j = 0; j < 16; ++j) {
            int i = base + t + j * 256;
            int b = -1, p = 0;
            if (i < N_EDGES) {
                int r = row[i], c = col[i];
                b = c >> CHUNK_LG;
                p = ((c & (CHUNK - 1)) << 17) | r;       // row < 2^17
                atomicAdd(&hist[b], 1);
            }
            myb[j] = b; myp[j] = p;
        }
        __syncthreads();
        for (int i = t; i < NBKT; i += 256) {
            int c = hist[i];
            sbase[i] = c ? atomicAdd(&gcur[i], c) : 0;
        }
        __syncthreads();
#pragma unroll
        for (int j = 0; j < 16; ++j) {
            int b = myb[j];
            if (b >= 0) {
                int pos = sbase[b] + atomicAdd(&lcur[b], 1);
                pairs[b * CAP + pos] = myp[j];
            }
        }
    }
}

// ============ Phase B: one block per bucket -> rowptr, dinv, srows ========
__global__ __launch_bounds__(256) void k_fillB(const int* __restrict__ gcur,
                                               const int* __restrict__ pairs,
                                               int* __restrict__ rowptr,
                                               float* __restrict__ dinv,
                                               int* __restrict__ srows) {
    __shared__ int mpl[CAP];
    __shared__ int red[256];
    __shared__ int psum[256];
    __shared__ int deg[CHUNK];
    __shared__ int curs[CHUNK];
    int b = blockIdx.x, t = threadIdx.x;

    int part = 0;
    for (int i = t; i < NBKT; i += 256)
        if (i < b) part += gcur[i];
    red[t] = part;
    deg[t] = 0;
    __syncthreads();
    for (int off = 128; off; off >>= 1) {
        if (t < off) red[t] += red[t + off];
        __syncthreads();
    }
    int gb = red[0];
    int cnt = gcur[b];
    if (b == 0 && t == 0) rowptr[N_NODES] = N_EDGES;

    int nbase = b << CHUNK_LG;
    const int* mp = pairs + b * CAP;

    for (int i = t; i < cnt; i += 256) {
        int v = mp[i];
        mpl[i] = v;
        atomicAdd(&deg[v >> 17], 1);
    }
    __syncthreads();

    int d = deg[t];
    psum[t] = d;
    __syncthreads();
    for (int off = 1; off < 256; off <<= 1) {
        int u = (t >= off) ? psum[t - off] : 0;
        __syncthreads();
        psum[t] += u;
        __syncthreads();
    }
    int o = gb + psum[t] - d;                 // exclusive
    curs[t] = o;
    int node = nbase + t;
    if (node < N_NODES) {
        rowptr[node] = o;
        dinv[node] = rsqrtf(1.f + (float)d);
    }
    __syncthreads();
    for (int i = t; i < cnt; i += 256) {
        int v = mpl[i];
        int pos = atomicAdd(&curs[v >> 17], 1);
        srows[pos] = v & 0x1FFFF;
    }
}

// ============ layer-2 GEMM: h2 = relu(agg1+b1)@W2, f16 out ================
template<int NOUT>
__global__ __launch_bounds__(256) void k_gemm_mfma2(
    const _Float16* __restrict__ Ah, const _Float16* __restrict__ Wt,
    const float* __restrict__ b_in, _Float16* __restrict__ Hout, int nrows)
{
    constexpr int KD = K_DIM;
    constexpr int NT = NOUT / 16;
    __shared__ _Float16 Blds[NOUT][KD + 8];

    for (int i = threadIdx.x; i < NOUT * (KD / 8); i += 256) {
        int n = i >> 4, k0 = (i & 15) * 8;
        *reinterpret_cast<half8*>(&Blds[n][k0]) =
            *reinterpret_cast<const half8*>(Wt + (size_t)n * KD + k0);
    }
    __syncthreads();

    const int wave = threadIdx.x >> 6;
    const int lane = threadIdx.x & 63;
    const int r16  = lane & 15;
    const int kg   = lane >> 4;
    const int arow = blockIdx.x * 64 + wave * 16 + r16;
    const bool rowok = arow < nrows;

    f32x4 acc[NT];
#pragma unroll
    for (int ct = 0; ct < NT; ++ct) acc[ct] = (f32x4){0.f, 0.f, 0.f, 0.f};

#pragma unroll
    for (int kc = 0; kc < KD / 32; ++kc) {
        const int k0 = kc * 32 + kg * 8;
        uint4 raw = make_uint4(0, 0, 0, 0);
        if (rowok)
            raw = *reinterpret_cast<const uint4*>(Ah + (size_t)arow * KD + k0);
        union { uint4 u; _Float16 h[8]; } U; U.u = raw;
        float4 bA = *reinterpret_cast<const float4*>(b_in + k0);
        float4 bB = *reinterpret_cast<const float4*>(b_in + k0 + 4);
        half8 a;
        a[0] = (_Float16)fmaxf((float)U.h[0] + bA.x, 0.f);
        a[1] = (_Float16)fmaxf((float)U.h[1] + bA.y, 0.f);
        a[2] = (_Float16)fmaxf((float)U.h[2] + bA.z, 0.f);
        a[3] = (_Float16)fmaxf((float)U.h[3] + bA.w, 0.f);
        a[4] = (_Float16)fmaxf((float)U.h[4] + bB.x, 0.f);
        a[5] = (_Float16)fmaxf((float)U.h[5] + bB.y, 0.f);
        a[6] = (_Float16)fmaxf((float)U.h[6] + bB.z, 0.f);
        a[7] = (_Float16)fmaxf((float)U.h[7] + bB.w, 0.f);
#pragma unroll
        for (int ct = 0; ct < NT; ++ct) {
            half8 b = *reinterpret_cast<const half8*>(&Blds[ct * 16 + r16][k0]);
            acc[ct] = __builtin_amdgcn_mfma_f32_16x16x32_f16(a, b, acc[ct], 0, 0, 0);
        }
    }

    const int orow0 = blockIdx.x * 64 + wave * 16 + kg * 4;
#pragma unroll
    for (int r = 0; r < 4; ++r) {
        int orow = orow0 + r;
        if (orow < nrows) {
#pragma unroll
            for (int ct = 0; ct < NT; ++ct)
                Hout[(size_t)orow * NOUT + ct * 16 + r16] = (_Float16)acc[ct][r];
        }
    }
}

// ---------------- gather (f16 source): one wave per destination ----------
__device__ __forceinline__ void fma8(uint4 v, float wgt, float (&acc)[8]) {
    union { uint4 u; _Float16 h[8]; } U;
    U.u = v;
#pragma unroll
    for (int j = 0; j < 8; ++j)
        acc[j] = fmaf((float)U.h[j], wgt, acc[j]);
}

// OUT[i] = sum_e H[row_e]*dinv_r*dinv_i + H[i]*dinv_i^2 (+bias)
template<int F, bool OUT_HALF>
__global__ __launch_bounds__(256) void k_gather_h(
    const int* __restrict__ rowptr, const int* __restrict__ srows,
    const float* __restrict__ dinv, const _Float16* __restrict__ H,
    const float* __restrict__ bias, void* __restrict__ OUT, int n)
{
    constexpr int LPR = F / 8;     // lanes per row (16 or 8), 8 f16 per lane
    constexpr int GR  = 64 / LPR;  // rows covered per wave-load (4 or 8)
    int w = blockIdx.x * 4 + (threadIdx.x >> 6);
    if (w >= n) return;
    int lane = threadIdx.x & 63;
    int g = lane / LPR;
    int c = lane % LPR;            // uint4 slot within row
    float di = dinv[w];
    int s = rowptr[w], e = rowptr[w + 1];
    const uint4* Hp = reinterpret_cast<const uint4*>(H);

    float acc[8];
#pragma unroll
    for (int j = 0; j < 8; ++j) acc[j] = 0.f;
    uint4 hv = Hp[(size_t)w * LPR + c];                 // self row
    fma8(hv, (g == 0) ? di * di : 0.f, acc);

    if (s < e) {
        int k0 = s + g;
        int kc = min(k0, e - 1);
        int r  = srows[kc];
        float wcur = (k0 < e) ? dinv[r] * di : 0.f;
        uint4 hcur = Hp[(size_t)r * LPR + c];
        for (int k = s + GR; k < e; k += GR) {
            int k1  = k + g;
            int kc1 = min(k1, e - 1);
            int r1  = srows[kc1];
            float wnxt = (k1 < e) ? dinv[r1] * di : 0.f;
            uint4 hnxt = Hp[(size_t)r1 * LPR + c];
            fma8(hcur, wcur, acc);
            wcur = wnxt; hcur = hnxt;
        }
        fma8(hcur, wcur, acc);
    }

#pragma unroll
    for (int m = 32; m >= LPR; m >>= 1) {               // combine row groups
#pragma unroll
        for (int j = 0; j < 8; ++j)
            acc[j] += __shfl_xor(acc[j], m, 64);
    }

    if (g == 0) {
        if constexpr (OUT_HALF) {
            union { uint4 u; __half2 h[4]; } P;
#pragma unroll
            for (int j = 0; j < 4; ++j)
                P.h[j] = __floats2half2_rn(acc[2 * j], acc[2 * j + 1]);
            reinterpret_cast<uint4*>(OUT)[(size_t)w * LPR + c] = P.u;
        } else {
            const float4* bp = reinterpret_cast<const float4*>(bias + c * 8);
            float4 b0 = bp[0], b1v = bp[1];
            float4 o0 = make_float4(acc[0] + b0.x, acc[1] + b0.y,
                                    acc[2] + b0.z, acc[3] + b0.w);
            float4 o1 = make_float4(acc[4] + b1v.x, acc[5] + b1v.y,
                                    acc[6] + b1v.z, acc[7] + b1v.w);
            float* op = (float*)OUT + (size_t)w * F + c * 8;
            *reinterpret_cast<float4*>(op)     = o0;
            *reinterpret_cast<float4*>(op + 4) = o1;
        }
    }
}

// ---------------- launch ----------------

extern "C" void kernel_launch(void* const* d_in, const int* in_sizes, int n_in,
                              void* d_out, int out_size, void* d_ws, size_t ws_size,
                              hipStream_t stream) {
    const float* x  = (const float*)d_in[0];
    const int*   ei = (const int*)  d_in[1];
    const float* W1 = (const float*)d_in[2];
    const float* b1 = (const float*)d_in[3];
    const float* W2 = (const float*)d_in[4];
    const float* b2 = (const float*)d_in[5];
    float* out = (float*)d_out;

    const int* row = ei;             // sources
    const int* col = ei + N_EDGES;   // targets

    // workspace layout
    char* ws = (char*)d_ws;
    int*   gcur   = (int*)ws;                                      // NBKT
    int*   rowptr = gcur + 512;                                    // N+1
    float* dinv   = (float*)(rowptr + ((N_NODES + 256) & ~255));   // N
    int*   srows  = (int*)(dinv + ((N_NODES + 255) & ~255));       // E
    _Float16* bufH  = (_Float16*)(srows + ((N_EDGES + 255) & ~255)); // N*128 (h1)
    _Float16* bufAgg = bufH + (size_t)N_NODES * 128;               // N*128 (agg1)
    _Float16* bufH2  = bufAgg + (size_t)N_NODES * 128;             // N*64 (h2)
    _Float16* Wt1 = bufH2 + (size_t)N_NODES * 64;                  // 128*128
    _Float16* Wt2 = Wt1 + 128 * 128;                               // 64*128
    int*   pairs  = (int*)(Wt2 + 64 * 128 + 256);                  // NBKT*CAP

    // 0) W -> f16 transposed (once); zero bucket cursors
    hipMemsetAsync(gcur, 0, NBKT * sizeof(int), stream);
    k_prepW<<<12, 256, 0, stream>>>(W1, W2, Wt1, Wt2);

    // 1) fused gemm1 ∥ edge bucketing (1:4 interleave)
    k_gemm1_bucket<<<NBLK_TOT, 256, 0, stream>>>(
        x, Wt1, bufH, row, col, gcur, pairs);

    // 2) CSR finalize: rowptr, dinv, srows
    k_fillB<<<NBKT, 256, 0, stream>>>(gcur, pairs, rowptr, dinv, srows);

    // 3) agg1 = gather(h1), f16 out
    k_gather_h<128, true><<<(N_NODES + 3) / 4, 256, 0, stream>>>(
        rowptr, srows, dinv, bufH, nullptr, bufAgg, N_NODES);

    // 4) h2 = relu(agg1+b1)@W2 (f16 out)
    k_gemm_mfma2<64><<<(N_NODES + 63) / 64, 256, 0, stream>>>(
        bufAgg, Wt2, b1, bufH2, N_NODES);

    // 5) out = gather(h2) + b2 (fp32 out)
    k_gather_h<64, false><<<(N_NODES + 3) / 4, 256, 0, stream>>>(
        rowptr, srows, dinv, bufH2, b2, out, N_NODES);
}

// Round 11
// 176.664 us; speedup vs baseline: 1.2253x; 1.0857x over previous
//
#include <hip/hip_runtime.h>
#include <hip/hip_fp16.h>

#define N_NODES 100000
#define N_EDGES 1600000
#define K_DIM   128

#define CHUNK_LG 7
#define CHUNK    128                                     // nodes per bucket
#define NBKT     ((N_NODES + CHUNK - 1) / CHUNK)         // 782
#define CAP      2560                                    // mean 2046 + ~11 sigma
#define EPB      4096                                    // edges per bucket-block
#define NBLK_A   ((N_EDGES + EPB - 1) / EPB)             // 391
#define G1_BLOCKS ((N_NODES + 63) / 64)                  // 1563 gemm tiles
#define NBLK_TOT (G1_BLOCKS + NBLK_A)                    // 1954

typedef _Float16 half8 __attribute__((ext_vector_type(8)));
typedef float    f32x4 __attribute__((ext_vector_type(4)));

// ============ one-shot: W -> f16 transposed Wt[n][k]; also zero gcur ======
__global__ __launch_bounds__(256) void k_prepW(const float* __restrict__ W1,
                                               const float* __restrict__ W2,
                                               _Float16* __restrict__ Wt1,
                                               _Float16* __restrict__ Wt2,
                                               int* __restrict__ gcur) {
    if (blockIdx.x >= 12) {                   // blocks 12..15: zero cursors
        int i = (blockIdx.x - 12) * 256 + threadIdx.x;
        if (i < NBKT) gcur[i] = 0;
        return;
    }
    int c = blockIdx.x * 256 + threadIdx.x;   // 3072 chunks of 8
    const float* W; _Float16* Wt; int nout;
    if (c < 2048) { W = W1; Wt = Wt1; nout = 128; }
    else          { W = W2; Wt = Wt2; nout = 64; c -= 2048; }
    int n  = c >> 4;
    int k0 = (c & 15) * 8;
    half8 v;
#pragma unroll
    for (int j = 0; j < 8; ++j)
        v[j] = (_Float16)W[(size_t)(k0 + j) * nout + n];
    *reinterpret_cast<half8*>(Wt + (size_t)n * K_DIM + k0) = v;
}

// ============ fused: gemm1 (h1 = x@W1, f16 out)  ∥  edge bucketing ========
// bid%5==0 -> bucket block (391, EPB=4096); else GEMM tile (1563).
__global__ __launch_bounds__(256) void k_gemm1_bucket(
    const float* __restrict__ x, const _Float16* __restrict__ Wt,
    _Float16* __restrict__ Hout,
    const int* __restrict__ row, const int* __restrict__ col,
    int* __restrict__ gcur, int* __restrict__ pairs)
{
    __shared__ __align__(16) char smem[128 * 136 * 2];   // 34816 B

    if (blockIdx.x % 5 != 0) {
        // ---------------- gemm path: NOUT=128, A fp32 ----------------
        constexpr int KD = K_DIM, NOUT = 128, NT = NOUT / 16;
        _Float16 (*Blds)[KD + 8] = reinterpret_cast<_Float16(*)[KD + 8]>(smem);

        for (int i = threadIdx.x; i < NOUT * (KD / 8); i += 256) {
            int n = i >> 4, k0 = (i & 15) * 8;
            *reinterpret_cast<half8*>(&Blds[n][k0]) =
                *reinterpret_cast<const half8*>(Wt + (size_t)n * KD + k0);
        }
        __syncthreads();

        const int tile = blockIdx.x - blockIdx.x / 5 - 1;
        const int wave = threadIdx.x >> 6;
        const int lane = threadIdx.x & 63;
        const int r16  = lane & 15;
        const int kg   = lane >> 4;
        const int arow = tile * 64 + wave * 16 + r16;
        const bool rowok = arow < N_NODES;

        f32x4 acc[NT];
#pragma unroll
        for (int ct = 0; ct < NT; ++ct) acc[ct] = (f32x4){0.f, 0.f, 0.f, 0.f};

#pragma unroll
        for (int kc = 0; kc < KD / 32; ++kc) {
            const int k0 = kc * 32 + kg * 8;
            float4 xa = make_float4(0.f, 0.f, 0.f, 0.f), xb = xa;
            if (rowok) {
                const float4* ap = reinterpret_cast<const float4*>(
                    x + (size_t)arow * KD + k0);
                xa = ap[0]; xb = ap[1];
            }
            half8 a;
            a[0] = (_Float16)xa.x; a[1] = (_Float16)xa.y;
            a[2] = (_Float16)xa.z; a[3] = (_Float16)xa.w;
            a[4] = (_Float16)xb.x; a[5] = (_Float16)xb.y;
            a[6] = (_Float16)xb.z; a[7] = (_Float16)xb.w;
#pragma unroll
            for (int ct = 0; ct < NT; ++ct) {
                half8 b = *reinterpret_cast<const half8*>(&Blds[ct * 16 + r16][k0]);
                acc[ct] = __builtin_amdgcn_mfma_f32_16x16x32_f16(a, b, acc[ct], 0, 0, 0);
            }
        }

        const int orow0 = tile * 64 + wave * 16 + kg * 4;
#pragma unroll
        for (int r = 0; r < 4; ++r) {
            int orow = orow0 + r;
            if (orow < N_NODES) {
#pragma unroll
                for (int ct = 0; ct < NT; ++ct)
                    Hout[(size_t)orow * NOUT + ct * 16 + r16] = (_Float16)acc[ct][r];
            }
        }
    } else {
        // ---------------- bucket path: EPB=4096, 16 edges/thread ---------
        int* hist  = (int*)smem;           // [1024]
        int* sbase = hist + 1024;          // [1024]
        int* lcur  = hist + 2048;          // [1024]
        int t = threadIdx.x;
        for (int i = t; i < NBKT; i += 256) { hist[i] = 0; lcur[i] = 0; }
        __syncthreads();
        int base = (blockIdx.x / 5) * EPB;
        int myb[16], myp[16];
#pragma unroll
        for (int j = 0; j < 16; ++j) {
            int i = base + t + j * 256;
            int b = -1, p = 0;
            if (i < N_EDGES) {
                int r = row[i], c = col[i];
                b = c >> CHUNK_LG;
                p = ((c & (CHUNK - 1)) << 17) | r;       // row < 2^17
                atomicAdd(&hist[b], 1);
            }
            myb[j] = b; myp[j] = p;
        }
        __syncthreads();
        for (int i = t; i < NBKT; i += 256) {
            int c = hist[i];
            sbase[i] = c ? atomicAdd(&gcur[i], c) : 0;
        }
        __syncthreads();
#pragma unroll
        for (int j = 0; j < 16; ++j) {
            int b = myb[j];
            if (b >= 0) {
                int pos = sbase[b] + atomicAdd(&lcur[b], 1);
                pairs[(size_t)b * CAP + pos] = myp[j];
            }
        }
    }
}

// ============ Phase B: one block per bucket (128 nodes) ===================
__global__ __launch_bounds__(256) void k_fillB(const int* __restrict__ gcur,
                                               const int* __restrict__ pairs,
                                               int* __restrict__ rowptr,
                                               float* __restrict__ dinv,
                                               int* __restrict__ srows) {
    __shared__ int mpl[CAP];
    __shared__ int red[256];
    __shared__ int psum[CHUNK];
    __shared__ int deg[CHUNK];
    __shared__ int curs[CHUNK];
    int b = blockIdx.x, t = threadIdx.x;

    // global base = sum gcur[0..b-1]
    int part = 0;
    for (int i = t; i < NBKT; i += 256)
        if (i < b) part += gcur[i];
    red[t] = part;
    if (t < CHUNK) deg[t] = 0;
    __syncthreads();
    for (int off = 128; off; off >>= 1) {
        if (t < off) red[t] += red[t + off];
        __syncthreads();
    }
    int gb = red[0];
    int cnt = gcur[b];
    if (b == 0 && t == 0) rowptr[N_NODES] = N_EDGES;

    const int* mp = pairs + (size_t)b * CAP;

    // stage + histogram in one pass
    for (int i = t; i < cnt; i += 256) {
        int v = mp[i];
        mpl[i] = v;
        atomicAdd(&deg[v >> 17], 1);
    }
    __syncthreads();

    int d = (t < CHUNK) ? deg[t] : 0;
    if (t < CHUNK) psum[t] = d;
    __syncthreads();
    for (int off = 1; off < CHUNK; off <<= 1) {
        int u = (t >= off && t < CHUNK) ? psum[t - off] : 0;
        __syncthreads();
        if (t < CHUNK) psum[t] += u;
        __syncthreads();
    }
    if (t < CHUNK) {
        int o = gb + psum[t] - d;                 // exclusive
        curs[t] = o;
        int node = (b << CHUNK_LG) + t;
        if (node < N_NODES) {
            rowptr[node] = o;
            dinv[node] = rsqrtf(1.f + (float)d);
        }
    }
    __syncthreads();
    for (int i = t; i < cnt; i += 256) {
        int v = mpl[i];
        int pos = atomicAdd(&curs[v >> 17], 1);
        srows[pos] = v & 0x1FFFF;
    }
}

// ============ layer-2 GEMM: h2 = relu(agg1+b1)@W2, f16 out ================
template<int NOUT>
__global__ __launch_bounds__(256) void k_gemm_mfma2(
    const _Float16* __restrict__ Ah, const _Float16* __restrict__ Wt,
    const float* __restrict__ b_in, _Float16* __restrict__ Hout, int nrows)
{
    constexpr int KD = K_DIM;
    constexpr int NT = NOUT / 16;
    __shared__ _Float16 Blds[NOUT][KD + 8];

    for (int i = threadIdx.x; i < NOUT * (KD / 8); i += 256) {
        int n = i >> 4, k0 = (i & 15) * 8;
        *reinterpret_cast<half8*>(&Blds[n][k0]) =
            *reinterpret_cast<const half8*>(Wt + (size_t)n * KD + k0);
    }
    __syncthreads();

    const int wave = threadIdx.x >> 6;
    const int lane = threadIdx.x & 63;
    const int r16  = lane & 15;
    const int kg   = lane >> 4;
    const int arow = blockIdx.x * 64 + wave * 16 + r16;
    const bool rowok = arow < nrows;

    f32x4 acc[NT];
#pragma unroll
    for (int ct = 0; ct < NT; ++ct) acc[ct] = (f32x4){0.f, 0.f, 0.f, 0.f};

#pragma unroll
    for (int kc = 0; kc < KD / 32; ++kc) {
        const int k0 = kc * 32 + kg * 8;
        uint4 raw = make_uint4(0, 0, 0, 0);
        if (rowok)
            raw = *reinterpret_cast<const uint4*>(Ah + (size_t)arow * KD + k0);
        union { uint4 u; _Float16 h[8]; } U; U.u = raw;
        float4 bA = *reinterpret_cast<const float4*>(b_in + k0);
        float4 bB = *reinterpret_cast<const float4*>(b_in + k0 + 4);
        half8 a;
        a[0] = (_Float16)fmaxf((float)U.h[0] + bA.x, 0.f);
        a[1] = (_Float16)fmaxf((float)U.h[1] + bA.y, 0.f);
        a[2] = (_Float16)fmaxf((float)U.h[2] + bA.z, 0.f);
        a[3] = (_Float16)fmaxf((float)U.h[3] + bA.w, 0.f);
        a[4] = (_Float16)fmaxf((float)U.h[4] + bB.x, 0.f);
        a[5] = (_Float16)fmaxf((float)U.h[5] + bB.y, 0.f);
        a[6] = (_Float16)fmaxf((float)U.h[6] + bB.z, 0.f);
        a[7] = (_Float16)fmaxf((float)U.h[7] + bB.w, 0.f);
#pragma unroll
        for (int ct = 0; ct < NT; ++ct) {
            half8 b = *reinterpret_cast<const half8*>(&Blds[ct * 16 + r16][k0]);
            acc[ct] = __builtin_amdgcn_mfma_f32_16x16x32_f16(a, b, acc[ct], 0, 0, 0);
        }
    }

    const int orow0 = blockIdx.x * 64 + wave * 16 + kg * 4;
#pragma unroll
    for (int r = 0; r < 4; ++r) {
        int orow = orow0 + r;
        if (orow < nrows) {
#pragma unroll
            for (int ct = 0; ct < NT; ++ct)
                Hout[(size_t)orow * NOUT + ct * 16 + r16] = (_Float16)acc[ct][r];
        }
    }
}

// ---------------- gather (f16 source): TWO nodes per wave ----------------
__device__ __forceinline__ void fma8(uint4 v, float wgt, float (&acc)[8]) {
    union { uint4 u; _Float16 h[8]; } U;
    U.u = v;
#pragma unroll
    for (int j = 0; j < 8; ++j)
        acc[j] = fmaf((float)U.h[j], wgt, acc[j]);
}

// OUT[i] = sum_e H[row_e]*dinv_r*dinv_i + H[i]*dinv_i^2 (+bias)
// Each 32-lane half-wave owns one destination node: halves per-node
// setup/reduce overhead and gives 2 independent load chains per wave.
template<int F, bool OUT_HALF>
__global__ __launch_bounds__(256) void k_gather_h(
    const int* __restrict__ rowptr, const int* __restrict__ srows,
    const float* __restrict__ dinv, const _Float16* __restrict__ H,
    const float* __restrict__ bias, void* __restrict__ OUT, int n)
{
    constexpr int LPR = F / 8;     // lanes per row (16 or 8)
    constexpr int GR  = 32 / LPR;  // rows per half-wave load (2 or 4)
    int lane = threadIdx.x & 63;
    int half = lane >> 5;
    int hl   = lane & 31;
    int w = blockIdx.x * 8 + (threadIdx.x >> 6) * 2 + half;
    if (w >= n) return;
    int g = hl / LPR;              // row group within half-wave
    int c = hl % LPR;              // uint4 slot within row
    float di = dinv[w];
    int s = rowptr[w], e = rowptr[w + 1];
    const uint4* Hp = reinterpret_cast<const uint4*>(H);

    float acc[8];
#pragma unroll
    for (int j = 0; j < 8; ++j) acc[j] = 0.f;
    uint4 hv = Hp[(size_t)w * LPR + c];                 // self row
    fma8(hv, (g == 0) ? di * di : 0.f, acc);

    if (s < e) {
        int k0 = s + g;
        int kc = min(k0, e - 1);
        int r  = srows[kc];
        float wcur = (k0 < e) ? dinv[r] * di : 0.f;
        uint4 hcur = Hp[(size_t)r * LPR + c];
        for (int k = s + GR; k < e; k += GR) {
            int k1  = k + g;
            int kc1 = min(k1, e - 1);
            int r1  = srows[kc1];
            float wnxt = (k1 < e) ? dinv[r1] * di : 0.f;
            uint4 hnxt = Hp[(size_t)r1 * LPR + c];
            fma8(hcur, wcur, acc);
            wcur = wnxt; hcur = hnxt;
        }
        fma8(hcur, wcur, acc);
    }

#pragma unroll
    for (int m = 16; m >= LPR; m >>= 1) {               // combine row groups
#pragma unroll
        for (int j = 0; j < 8; ++j)
            acc[j] += __shfl_xor(acc[j], m, 64);
    }

    if (g == 0) {
        if constexpr (OUT_HALF) {
            union { uint4 u; __half2 h[4]; } P;
#pragma unroll
            for (int j = 0; j < 4; ++j)
                P.h[j] = __floats2half2_rn(acc[2 * j], acc[2 * j + 1]);
            reinterpret_cast<uint4*>(OUT)[(size_t)w * LPR + c] = P.u;
        } else {
            const float4* bp = reinterpret_cast<const float4*>(bias + c * 8);
            float4 b0 = bp[0], b1v = bp[1];
            float4 o0 = make_float4(acc[0] + b0.x, acc[1] + b0.y,
                                    acc[2] + b0.z, acc[3] + b0.w);
            float4 o1 = make_float4(acc[4] + b1v.x, acc[5] + b1v.y,
                                    acc[6] + b1v.z, acc[7] + b1v.w);
            float* op = (float*)OUT + (size_t)w * F + c * 8;
            *reinterpret_cast<float4*>(op)     = o0;
            *reinterpret_cast<float4*>(op + 4) = o1;
        }
    }
}

// ---------------- launch ----------------

extern "C" void kernel_launch(void* const* d_in, const int* in_sizes, int n_in,
                              void* d_out, int out_size, void* d_ws, size_t ws_size,
                              hipStream_t stream) {
    const float* x  = (const float*)d_in[0];
    const int*   ei = (const int*)  d_in[1];
    const float* W1 = (const float*)d_in[2];
    const float* b1 = (const float*)d_in[3];
    const float* W2 = (const float*)d_in[4];
    const float* b2 = (const float*)d_in[5];
    float* out = (float*)d_out;

    const int* row = ei;             // sources
    const int* col = ei + N_EDGES;   // targets

    // workspace layout
    char* ws = (char*)d_ws;
    int*   gcur   = (int*)ws;                                      // NBKT (782)
    int*   rowptr = gcur + 1024;                                   // N+1
    float* dinv   = (float*)(rowptr + ((N_NODES + 256) & ~255));   // N
    int*   srows  = (int*)(dinv + ((N_NODES + 255) & ~255));       // E
    _Float16* bufH  = (_Float16*)(srows + ((N_EDGES + 255) & ~255)); // N*128 (h1)
    _Float16* bufAgg = bufH + (size_t)N_NODES * 128;               // N*128 (agg1)
    _Float16* bufH2  = bufAgg + (size_t)N_NODES * 128;             // N*64 (h2)
    _Float16* Wt1 = bufH2 + (size_t)N_NODES * 64;                  // 128*128
    _Float16* Wt2 = Wt1 + 128 * 128;                               // 64*128
    int*   pairs  = (int*)(Wt2 + 64 * 128 + 256);                  // NBKT*CAP (8MB)

    // 0) W -> f16 transposed + zero bucket cursors (one launch)
    k_prepW<<<16, 256, 0, stream>>>(W1, W2, Wt1, Wt2, gcur);

    // 1) fused gemm1 ∥ edge bucketing (1:4 interleave)
    k_gemm1_bucket<<<NBLK_TOT, 256, 0, stream>>>(
        x, Wt1, bufH, row, col, gcur, pairs);

    // 2) CSR finalize: rowptr, dinv, srows (782 blocks)
    k_fillB<<<NBKT, 256, 0, stream>>>(gcur, pairs, rowptr, dinv, srows);

    // 3) agg1 = gather(h1), f16 out  (2 nodes per wave)
    k_gather_h<128, true><<<(N_NODES + 7) / 8, 256, 0, stream>>>(
        rowptr, srows, dinv, bufH, nullptr, bufAgg, N_NODES);

    // 4) h2 = relu(agg1+b1)@W2 (f16 out)
    k_gemm_mfma2<64><<<(N_NODES + 63) / 64, 256, 0, stream>>>(
        bufAgg, Wt2, b1, bufH2, N_NODES);

    // 5) out = gather(h2) + b2 (fp32 out, 2 nodes per wave)
    k_gather_h<64, false><<<(N_NODES + 7) / 8, 256, 0, stream>>>(
        rowptr, srows, dinv, bufH2, b2, out, N_NODES);
}